// Round 6
// baseline (654.884 us; speedup 1.0000x reference)
//
#include <hip/hip_runtime.h>
#include <stdint.h>

#define D 512

typedef _Float16 f16;
typedef f16 f16x8 __attribute__((ext_vector_type(8)));
typedef f16 h2 __attribute__((ext_vector_type(2)));
typedef float f32x4 __attribute__((ext_vector_type(4)));
typedef float f32x16 __attribute__((ext_vector_type(16)));
typedef unsigned int u32;
typedef u32 u32x4 __attribute__((ext_vector_type(4)));

static __device__ __forceinline__ u32 bcu(h2 h) { return __builtin_bit_cast(u32, h); }
static __device__ __forceinline__ h2 pkrtz(float a, float b) {
  return __builtin_bit_cast(h2, __builtin_amdgcn_cvt_pkrtz(a, b));
}
static __device__ __forceinline__ f16x8 frag4(u32 w0, u32 w1, u32 w2, u32 w3) {
  u32x4 u = {w0, w1, w2, w3};
  return __builtin_bit_cast(f16x8, u);
}
static __device__ __forceinline__ float fastrcp(float x) {
#if __has_builtin(__builtin_amdgcn_rcpf)
  return __builtin_amdgcn_rcpf(x);
#else
  return 1.0f / x;
#endif
}

// ---------------- prep: Wcat f16 [h][k|v][d][i] + bcat + Wqh f16 [o][i] ----------------
__global__ __launch_bounds__(256) void prep_k(
    const float* __restrict__ Wq, const float* __restrict__ Wk,
    const float* __restrict__ bk, const float* __restrict__ Wv,
    const float* __restrict__ bv, f16* __restrict__ Wcat,
    float* __restrict__ bcat, f16* __restrict__ Wqh) {
  int bid = blockIdx.x, tid = threadIdx.x;
  if (bid < 1024) {
    int h = bid >> 7, kvs = (bid >> 6) & 1, d = bid & 63;
    int srow = h * 64 + d;
    const float* src = (kvs ? Wv : Wk) + (size_t)srow * D;
    f16* dst = Wcat + (size_t)bid * D;
    for (int i = tid; i < D; i += 256) dst[i] = (f16)src[i];
    if (tid == 0) bcat[bid] = (kvs ? bv : bk)[srow];
  } else {
    int o = bid - 1024;
    for (int i = tid; i < D; i += 256) Wqh[(size_t)o * D + i] = (f16)Wq[(size_t)o * D + i];
  }
}

// ---------------- qproj (MFMA): q16h[h][bs][n][64] = LN(xf) @ Wq^T + bq ----------------
__global__ __launch_bounds__(256) void qproj_k(
    const float* __restrict__ xf, const float* __restrict__ tn_g,
    const float* __restrict__ tn_b, const f16* __restrict__ Wqh,
    const float* __restrict__ bq, f16* __restrict__ q16h) {
  __shared__ __align__(16) unsigned char lds[16384];
  const int bs = blockIdx.x, n0 = blockIdx.y * 16;
  const int tid = threadIdx.x, wv = tid >> 6, lane = tid & 63;
  const int l15 = lane & 15, lhi = lane >> 4;

  for (int rr = wv; rr < 16; rr += 4) {
    int srcn = n0 + rr;
    if (srcn > 76) srcn = 76;
    const f32x4* xr = (const f32x4*)(xf + ((size_t)(bs * 77 + srcn)) * D);
    f32x4 va = xr[lane * 2], vb = xr[lane * 2 + 1];
    float s = va[0] + va[1] + va[2] + va[3] + vb[0] + vb[1] + vb[2] + vb[3];
    float sq = va[0] * va[0] + va[1] * va[1] + va[2] * va[2] + va[3] * va[3] +
               vb[0] * vb[0] + vb[1] * vb[1] + vb[2] * vb[2] + vb[3] * vb[3];
#pragma unroll
    for (int off = 32; off; off >>= 1) {
      s += __shfl_xor(s, off);
      sq += __shfl_xor(sq, off);
    }
    float mu = s * (1.0f / 512.0f);
    float var = sq * (1.0f / 512.0f) - mu * mu;
    float rstd = rsqrtf(var + 1e-5f);
    f32x4 ga = ((const f32x4*)tn_g)[lane * 2], gb = ((const f32x4*)tn_g)[lane * 2 + 1];
    f32x4 ba = ((const f32x4*)tn_b)[lane * 2], bb = ((const f32x4*)tn_b)[lane * 2 + 1];
    uint4 u;
    u.x = bcu(pkrtz((va[0] - mu) * rstd * ga[0] + ba[0], (va[1] - mu) * rstd * ga[1] + ba[1]));
    u.y = bcu(pkrtz((va[2] - mu) * rstd * ga[2] + ba[2], (va[3] - mu) * rstd * ga[3] + ba[3]));
    u.z = bcu(pkrtz((vb[0] - mu) * rstd * gb[0] + bb[0], (vb[1] - mu) * rstd * gb[1] + bb[1]));
    u.w = bcu(pkrtz((vb[2] - mu) * rstd * gb[2] + bb[2], (vb[3] - mu) * rstd * gb[3] + bb[3]));
    *reinterpret_cast<uint4*>(lds + rr * 1024 + ((lane * 16) ^ ((rr & 7) << 4))) = u;
  }
  __syncthreads();

  f32x4 acc[8];
#pragma unroll
  for (int nt = 0; nt < 8; ++nt) {
    float bias = bq[wv * 128 + nt * 16 + l15];
    acc[nt] = (f32x4){bias, bias, bias, bias};
  }
  for (int ks = 0; ks < 16; ++ks) {
    f16x8 af = *(const f16x8*)(lds + l15 * 1024 + ((ks * 64 + lhi * 16) ^ ((l15 & 7) << 4)));
#pragma unroll
    for (int nt = 0; nt < 8; ++nt) {
      f16x8 bf = *(const f16x8*)(Wqh + (size_t)(wv * 128 + nt * 16 + l15) * D + ks * 32 + lhi * 8);
      acc[nt] = __builtin_amdgcn_mfma_f32_16x16x32_f16(af, bf, acc[nt], 0, 0, 0);
    }
  }
#pragma unroll
  for (int nt = 0; nt < 8; ++nt) {
    int col = wv * 128 + nt * 16 + l15;
    int h = col >> 6, d = col & 63;
    f16* base = q16h + ((size_t)(h * 16 + bs) * 77) * 64;
#pragma unroll
    for (int r = 0; r < 4; ++r) {
      int n = n0 + lhi * 4 + r;
      if (n < 77) base[n * 64 + d] = (f16)acc[nt][r];
    }
  }
}

// ---------------- projkv: LN(x) + GEMM -> Kbuf [b][h][17][64], Vtbuf [b][h][64][24] ----------------
// BM=64 rows (flat over b*17+t), full K=512 in LDS (64KB, swizzled), one barrier.
// 4 waves x 256 cols each; 32x32x16 MFMA; grid 1033.
__global__ __launch_bounds__(256, 2) void projkv_k(
    const float* __restrict__ x, const float* __restrict__ n_g,
    const float* __restrict__ n_b, const f16* __restrict__ Wcat,
    const float* __restrict__ bcat, f16* __restrict__ Kbuf, f16* __restrict__ Vtbuf) {
  __shared__ __align__(16) unsigned char lds[65536];
  const int tid = threadIdx.x, wv = tid >> 6, lane = tid & 63;
  const int l31 = lane & 31, hi = lane >> 5;
  const int r0 = blockIdx.x * 64;

  // LN: 64 rows (clamped at tail)
  for (int i = 0; i < 16; ++i) {
    int rr = wv * 16 + i;
    int grow = r0 + rr;
    if (grow > 66095) grow = 66095;
    const f32x4* xr = (const f32x4*)(x + (size_t)grow * D);
    f32x4 va = xr[lane * 2], vb = xr[lane * 2 + 1];
    float s = va[0] + va[1] + va[2] + va[3] + vb[0] + vb[1] + vb[2] + vb[3];
    float sq = va[0] * va[0] + va[1] * va[1] + va[2] * va[2] + va[3] * va[3] +
               vb[0] * vb[0] + vb[1] * vb[1] + vb[2] * vb[2] + vb[3] * vb[3];
#pragma unroll
    for (int off = 32; off; off >>= 1) {
      s += __shfl_xor(s, off);
      sq += __shfl_xor(sq, off);
    }
    float mu = s * (1.0f / 512.0f);
    float var = sq * (1.0f / 512.0f) - mu * mu;
    float rstd = rsqrtf(var + 1e-5f);
    f32x4 ga = ((const f32x4*)n_g)[lane * 2], gb = ((const f32x4*)n_g)[lane * 2 + 1];
    f32x4 ba = ((const f32x4*)n_b)[lane * 2], bb = ((const f32x4*)n_b)[lane * 2 + 1];
    uint4 u;
    u.x = bcu(pkrtz((va[0] - mu) * rstd * ga[0] + ba[0], (va[1] - mu) * rstd * ga[1] + ba[1]));
    u.y = bcu(pkrtz((va[2] - mu) * rstd * ga[2] + ba[2], (va[3] - mu) * rstd * ga[3] + ba[3]));
    u.z = bcu(pkrtz((vb[0] - mu) * rstd * gb[0] + bb[0], (vb[1] - mu) * rstd * gb[1] + bb[1]));
    u.w = bcu(pkrtz((vb[2] - mu) * rstd * gb[2] + bb[2], (vb[3] - mu) * rstd * gb[3] + bb[3]));
    *reinterpret_cast<uint4*>(lds + rr * 1024 + ((lane * 16) ^ ((rr & 7) << 4))) = u;
  }
  __syncthreads();

  // GEMM: this wave covers cols [wv*256, wv*256+256), 4 groups of 2 ntiles(32)
  for (int g = 0; g < 4; ++g) {
    const int cb = wv * 256 + g * 64;
    f32x16 acc[2][2];
#pragma unroll
    for (int ntt = 0; ntt < 2; ++ntt) {
      float bias = bcat[cb + ntt * 32 + l31];
#pragma unroll
      for (int mt = 0; mt < 2; ++mt)
#pragma unroll
        for (int q = 0; q < 16; ++q) acc[mt][ntt][q] = bias;
    }
    const f16* wb0 = Wcat + (size_t)(cb + l31) * D;
    const f16* wb1 = Wcat + (size_t)(cb + 32 + l31) * D;
#pragma unroll 4
    for (int kc = 0; kc < 32; ++kc) {
      int row0 = l31, row1 = 32 + l31;
      f16x8 a0 = *(const f16x8*)(lds + row0 * 1024 + ((kc * 32 + hi * 16) ^ ((row0 & 7) << 4)));
      f16x8 a1 = *(const f16x8*)(lds + row1 * 1024 + ((kc * 32 + hi * 16) ^ ((row1 & 7) << 4)));
      f16x8 b0 = *(const f16x8*)(wb0 + kc * 16 + hi * 8);
      f16x8 b1 = *(const f16x8*)(wb1 + kc * 16 + hi * 8);
      acc[0][0] = __builtin_amdgcn_mfma_f32_32x32x16_f16(a0, b0, acc[0][0], 0, 0, 0);
      acc[0][1] = __builtin_amdgcn_mfma_f32_32x32x16_f16(a0, b1, acc[0][1], 0, 0, 0);
      acc[1][0] = __builtin_amdgcn_mfma_f32_32x32x16_f16(a1, b0, acc[1][0], 0, 0, 0);
      acc[1][1] = __builtin_amdgcn_mfma_f32_32x32x16_f16(a1, b1, acc[1][1], 0, 0, 0);
    }
    // store: col c -> (h, k|v, d); row grow -> (b, t) via magic /17
#pragma unroll
    for (int mt = 0; mt < 2; ++mt) {
#pragma unroll
      for (int ntt = 0; ntt < 2; ++ntt) {
        int c = cb + ntt * 32 + l31;
        int h = c >> 7, kv = (c >> 6) & 1, d = c & 63;
#pragma unroll
        for (int q = 0; q < 16; ++q) {
          int grow = r0 + mt * 32 + (q & 3) + 8 * (q >> 2) + 4 * hi;
          if (grow < 66096) {
            u32 bb2 = ((u32)grow * 61681u) >> 20;
            int t = grow - (int)bb2 * 17;
            f16 v = (f16)acc[mt][ntt][q];
            if (kv == 0)
              Kbuf[((size_t)(bb2 * 8 + h) * 17 + t) * 64 + d] = v;
            else
              Vtbuf[((size_t)(bb2 * 8 + h) * 64 + d) * 24 + t] = v;
          }
        }
      }
    }
  }
}

// ---------------- attn: per-wave batch, 8 heads x 3 ntiles(32), no LDS, no barriers ----------------
__global__ __launch_bounds__(256, 4) void attn_k(
    const f16* __restrict__ q16h, const f16* __restrict__ Kbuf,
    const f16* __restrict__ Vtbuf, float* __restrict__ out) {
  const int wv = threadIdx.x >> 6, lane = threadIdx.x & 63;
  const int b = blockIdx.x * 4 + wv, bs = b & 15;
  const int l31 = lane & 31, hi = lane >> 5;
  const float C2 = 0.18033688011112042f;  // log2(e)/8
  const int mc = l31 > 16 ? 16 : l31;

  for (int h = 0; h < 8; ++h) {
    const f16* kb = Kbuf + (size_t)(b * 8 + h) * 17 * 64;
    const f16* vtb = Vtbuf + (size_t)(b * 8 + h) * 64 * 24;
    const f16* qb = q16h + ((size_t)(h * 16 + bs) * 77) * 64;
    float* ob = out + (size_t)b * 77 * 512 + h * 64;

    // K A-frags: row m = l31 (clamped), k = dc*16 + hi*8 + j
    f16x8 kf[4];
#pragma unroll
    for (int dc = 0; dc < 4; ++dc) kf[dc] = *(const f16x8*)(kb + mc * 64 + dc * 16 + hi * 8);
    // Vt B-frags: col d = dg*32 + l31, k rows m = ch*16 + hi*8 + j
    f16x8 vf[2][2];
#pragma unroll
    for (int dg = 0; dg < 2; ++dg)
#pragma unroll
      for (int ch = 0; ch < 2; ++ch)
        vf[dg][ch] = *(const f16x8*)(vtb + (size_t)(dg * 32 + l31) * 24 + ch * 16 + hi * 8);

#pragma unroll
    for (int nt = 0; nt < 3; ++nt) {
      int nq = nt * 32 + l31;
      if (nq > 76) nq = 76;
      f32x16 s;
#pragma unroll
      for (int q = 0; q < 16; ++q) s[q] = 0.f;
#pragma unroll
      for (int dc = 0; dc < 4; ++dc) {
        f16x8 qf = *(const f16x8*)(qb + nq * 64 + dc * 16 + hi * 8);
        s = __builtin_amdgcn_mfma_f32_32x32x16_f16(kf[dc], qf, s, 0, 0, 0);
      }
      // masked softmax over m: valid regs 0..7 (both hi) + reg 8 (hi==0, m=16)
      float mx = s[0];
#pragma unroll
      for (int q = 1; q < 8; ++q) mx = fmaxf(mx, s[q]);
      if (hi == 0) mx = fmaxf(mx, s[8]);
      mx = fmaxf(mx, __shfl_xor(mx, 32));
      float e[8], sum = 0.f;
#pragma unroll
      for (int q = 0; q < 8; ++q) {
        e[q] = exp2f((s[q] - mx) * C2);
        sum += e[q];
      }
      float e8 = (hi == 0) ? exp2f((s[8] - mx) * C2) : 0.f;
      sum += e8;
      sum += __shfl_xor(sum, 32);
      float inv = fastrcp(sum);
#pragma unroll
      for (int q = 0; q < 8; ++q) e[q] *= inv;
      e8 *= inv;
      // repack P^T (C-layout) -> PV A-frags
      u32 u0 = bcu(pkrtz(e[0], e[1])), u1 = bcu(pkrtz(e[2], e[3]));
      u32 u2 = bcu(pkrtz(e[4], e[5])), u3 = bcu(pkrtz(e[6], e[7]));
      u32 p0 = (u32)__shfl_xor((int)u0, 32), p1 = (u32)__shfl_xor((int)u1, 32);
      u32 p2 = (u32)__shfl_xor((int)u2, 32), p3 = (u32)__shfl_xor((int)u3, 32);
      f16x8 pa0 = (hi == 0) ? frag4(u0, u1, p0, p1) : frag4(p2, p3, u2, u3);
      f16x8 pa1 = frag4((hi == 0) ? bcu(pkrtz(e8, 0.f)) : 0u, 0u, 0u, 0u);
#pragma unroll
      for (int dg = 0; dg < 2; ++dg) {
        f32x16 o;
#pragma unroll
        for (int q = 0; q < 16; ++q) o[q] = 0.f;
        o = __builtin_amdgcn_mfma_f32_32x32x16_f16(pa0, vf[dg][0], o, 0, 0, 0);
        o = __builtin_amdgcn_mfma_f32_32x32x16_f16(pa1, vf[dg][1], o, 0, 0, 0);
#pragma unroll
        for (int q = 0; q < 16; ++q) {
          int n = nt * 32 + (q & 3) + 8 * (q >> 2) + 4 * hi;
          if (n < 77) ob[(size_t)n * 512 + dg * 32 + l31] = o[q];
        }
      }
    }
  }
}

extern "C" void kernel_launch(void* const* d_in, const int* in_sizes, int n_in,
                              void* d_out, int out_size, void* d_ws, size_t ws_size,
                              hipStream_t stream) {
  const float* xf = (const float*)d_in[0];
  const float* x = (const float*)d_in[1];
  const float* tn_g = (const float*)d_in[2];
  const float* tn_b = (const float*)d_in[3];
  const float* n_g = (const float*)d_in[4];
  const float* n_b = (const float*)d_in[5];
  const float* Wq = (const float*)d_in[6];
  const float* bq = (const float*)d_in[7];
  const float* Wk = (const float*)d_in[8];
  const float* bk = (const float*)d_in[9];
  const float* Wv = (const float*)d_in[10];
  const float* bv = (const float*)d_in[11];
  float* out = (float*)d_out;

  char* ws = (char*)d_ws;
  f16* q16h = (f16*)ws;                       // 8*16*77*64*2      = 1,261,568
  f16* Wcat = (f16*)(ws + 1261568);           // 1024*512*2        = 1,048,576
  f16* Wqh = (f16*)(ws + 2310144);            // 512*512*2         = 524,288
  float* bcat = (float*)(ws + 2834432);       // 1024*4            = 4,096
  f16* Kbuf = (f16*)(ws + 2838528);           // 3888*8*17*64*2    = 67,682,304
  f16* Vtbuf = (f16*)(ws + 70520832);         // 3888*8*64*24*2    = 95,551,488 (+pad)
                                              // total ~166.1 MB

  prep_k<<<1536, 256, 0, stream>>>(Wq, Wk, bk, Wv, bv, Wcat, bcat, Wqh);
  qproj_k<<<dim3(16, 5), 256, 0, stream>>>(xf, tn_g, tn_b, Wqh, bq, q16h);
  projkv_k<<<1033, 256, 0, stream>>>(x, n_g, n_b, Wcat, bcat, Kbuf, Vtbuf);
  attn_k<<<972, 256, 0, stream>>>(q16h, Kbuf, Vtbuf, out);
}